// Round 1
// baseline (829.052 us; speedup 1.0000x reference)
//
#include <hip/hip_runtime.h>
#include <hip/hip_bf16.h>

#define CCH 384
#define HH 56
#define WW 56
#define TH 8
#define TW 8
#define TP 64
#define QMAX 7.0f
#define SCALE_MIN 2e-16f

// ---------------- quant kernels (Brevitas per-channel symmetric int4) -------

__global__ void quant_dw(const float* __restrict__ dw, float* __restrict__ dwq) {
    int c = blockIdx.x * blockDim.x + threadIdx.x;
    if (c >= CCH) return;
    float w[9];
    float amax = 0.f;
    #pragma unroll
    for (int j = 0; j < 9; ++j) {
        w[j] = dw[c * 9 + j];
        amax = fmaxf(amax, fabsf(w[j]));
    }
    float scale = fmaxf(amax / QMAX, SCALE_MIN);
    #pragma unroll
    for (int j = 0; j < 9; ++j) {
        float q = rintf(w[j] / scale);          // round half-to-even, matches jnp.round
        q = fminf(fmaxf(q, -QMAX), QMAX);
        dwq[c * 9 + j] = q * scale;
    }
}

// one block (64 threads) per output channel; writes TRANSPOSED pwq_t[ci][co]
__global__ void quant_pw(const float* __restrict__ pw, float* __restrict__ pwq_t) {
    int co = blockIdx.x;
    int lane = threadIdx.x;   // 0..63
    float w[6];
    float amax = 0.f;
    #pragma unroll
    for (int j = 0; j < 6; ++j) {
        w[j] = pw[co * CCH + lane + j * 64];
        amax = fmaxf(amax, fabsf(w[j]));
    }
    #pragma unroll
    for (int off = 32; off >= 1; off >>= 1)
        amax = fmaxf(amax, __shfl_xor(amax, off));
    float scale = fmaxf(amax / QMAX, SCALE_MIN);
    #pragma unroll
    for (int j = 0; j < 6; ++j) {
        float q = rintf(w[j] / scale);
        q = fminf(fmaxf(q, -QMAX), QMAX);
        pwq_t[(size_t)(lane + j * 64) * CCH + co] = q * scale;
    }
}

// ---------------- fused depthwise 3x3 + pointwise 1x1 + bias ----------------
// Block: 256 threads (4 waves). Tile: 8x8 spatial positions, one (n, tile).
// Phase 1: wave g computes depthwise y for ci in [96g, 96g+96) -> LDS (bf16).
// Phase 2: wave g computes output channels [96g, 96g+96) for its 64 positions.

__global__ __launch_bounds__(256) void fused_conv(
    const float* __restrict__ x, const float* __restrict__ dwq,
    const float* __restrict__ pwq_t, const float* __restrict__ bias,
    float* __restrict__ out)
{
    __shared__ __hip_bfloat16 y_sh[CCH][TP];    // 48 KB

    const int tid = threadIdx.x;
    const int lane = tid & 63;
    const int g = __builtin_amdgcn_readfirstlane(tid >> 6);   // wave id 0..3

    const int n  = blockIdx.z;
    const int h0 = blockIdx.y * TH;
    const int w0 = blockIdx.x * TW;
    const int hh = lane >> 3, ww = lane & 7;
    const int h = h0 + hh, w = w0 + ww;

    // ---- phase 1: depthwise 3x3, stride 1, pad 1 ----
    const float* xn = x + (size_t)n * CCH * (HH * WW);
    for (int t = 0; t < 96; ++t) {
        const int ci = g * 96 + t;
        const float* xp = xn + (size_t)ci * (HH * WW);
        const float* dk = dwq + ci * 9;
        float acc = 0.f;
        #pragma unroll
        for (int r = 0; r < 3; ++r) {
            const int xh = h + r - 1;
            const bool okh = ((unsigned)xh < (unsigned)HH);
            #pragma unroll
            for (int s = 0; s < 3; ++s) {
                const int xw = w + s - 1;
                const bool ok = okh && ((unsigned)xw < (unsigned)WW);
                const float xv = ok ? xp[xh * WW + xw] : 0.f;
                acc = fmaf(xv, dk[r * 3 + s], acc);
            }
        }
        y_sh[ci][lane] = __float2bfloat16(acc);
    }
    __syncthreads();

    // ---- phase 2: pointwise 1x1 over all 384 ci ----
    const int co_base = g * 96;
    float acc[96];
    #pragma unroll
    for (int k = 0; k < 96; ++k) acc[k] = 0.f;

    for (int ci = 0; ci < CCH; ++ci) {
        const float yv = __bfloat162float(y_sh[ci][lane]);
        const float* prow = pwq_t + (size_t)ci * CCH + co_base;  // wave-uniform
        #pragma unroll
        for (int k = 0; k < 96; ++k)
            acc[k] = fmaf(yv, prow[k], acc[k]);
    }

    // ---- epilogue: bias + store ----
    float* ob = out + (size_t)n * CCH * (HH * WW) + h * WW + w;
    #pragma unroll
    for (int k = 0; k < 96; ++k) {
        const int co = co_base + k;
        ob[(size_t)co * (HH * WW)] = acc[k] + bias[co];
    }
}

// ---------------------------------------------------------------------------

extern "C" void kernel_launch(void* const* d_in, const int* in_sizes, int n_in,
                              void* d_out, int out_size, void* d_ws, size_t ws_size,
                              hipStream_t stream) {
    const float* x  = (const float*)d_in[0];
    const float* dw = (const float*)d_in[1];
    const float* pw = (const float*)d_in[2];
    const float* pb = (const float*)d_in[3];
    float* out = (float*)d_out;

    float* dwq   = (float*)d_ws;            // 384*9 floats
    float* pwq_t = dwq + CCH * 9;           // 384*384 floats, transposed [ci][co]

    quant_dw<<<2, 256, 0, stream>>>(dw, dwq);
    quant_pw<<<CCH, 64, 0, stream>>>(pw, pwq_t);

    dim3 grid(WW / TW, HH / TH, 32);        // 7 x 7 x 32
    fused_conv<<<grid, 256, 0, stream>>>(x, dwq, pwq_t, pb, out);
}

// Round 2
// 356.859 us; speedup vs baseline: 2.3232x; 2.3232x over previous
//
#include <hip/hip_runtime.h>
#include <hip/hip_bf16.h>

#define CCH 384
#define HW2 3136            // 56*56
#define HH 56
#define WW 56
#define QMAX 7.0f
#define SCALE_MIN 2e-16f

typedef _Float16 half8 __attribute__((ext_vector_type(8)));
typedef float f32x4 __attribute__((ext_vector_type(4)));

// ---------------- quant kernels (Brevitas per-channel symmetric int4) -------

__global__ void quant_dw(const float* __restrict__ dw, float* __restrict__ dwq) {
    int c = blockIdx.x * blockDim.x + threadIdx.x;
    if (c >= CCH) return;
    float w[9];
    float amax = 0.f;
    #pragma unroll
    for (int j = 0; j < 9; ++j) {
        w[j] = dw[c * 9 + j];
        amax = fmaxf(amax, fabsf(w[j]));
    }
    float scale = fmaxf(amax / QMAX, SCALE_MIN);
    #pragma unroll
    for (int j = 0; j < 9; ++j) {
        float q = rintf(w[j] / scale);          // round half-even = jnp.round
        q = fminf(fmaxf(q, -QMAX), QMAX);
        dwq[c * 9 + j] = q * scale;             // keep depthwise weights f32
    }
}

// one block (64 threads) per output channel; fake-quant then pack fp16 into
// MFMA A-fragment layout: wpk[(ci/32)*24 + co/16][lane][8]
//   lane = (co&15) + ((ci%32)/8)*16 ; j = ci%8
__global__ void quant_pw(const float* __restrict__ pw, _Float16* __restrict__ wpk) {
    int co = blockIdx.x;
    int lane = threadIdx.x;   // 0..63
    float w[6];
    float amax = 0.f;
    #pragma unroll
    for (int j = 0; j < 6; ++j) {
        w[j] = pw[co * CCH + lane + j * 64];
        amax = fmaxf(amax, fabsf(w[j]));
    }
    #pragma unroll
    for (int off = 32; off >= 1; off >>= 1)
        amax = fmaxf(amax, __shfl_xor(amax, off));
    float scale = fmaxf(amax / QMAX, SCALE_MIN);
    #pragma unroll
    for (int j = 0; j < 6; ++j) {
        int ci = lane + j * 64;
        float q = rintf(w[j] / scale);
        q = fminf(fmaxf(q, -QMAX), QMAX);
        float v = q * scale;
        int kk  = ci >> 5;
        int cis = ci & 31;
        int l   = (co & 15) | ((cis >> 3) << 4);
        int idx = (kk * 24 + (co >> 4)) * 512 + l * 8 + (cis & 7);
        wpk[idx] = (_Float16)v;
    }
}

// ---------------- fused depthwise 3x3 + MFMA pointwise 1x1 + bias -----------
// Block: 256 threads (4 waves), one (n, 8x8 spatial tile).
// Phase 1: wave g computes depthwise y for ci in [96g,96g+96) -> LDS fp16,
//          y_sh[pos][ci] with 16B XOR swizzle (^ (pos&7)<<4).
// Phase 2: wave g computes co in [96g,96g+96) x 64 pos via 6x4 MFMA frags,
//          K-loop over 12 ci-steps of 32. Weights stream from L2 (packed).

__global__ __launch_bounds__(256, 2) void fused_conv(
    const float* __restrict__ x, const float* __restrict__ dwq,
    const _Float16* __restrict__ wpk, const float* __restrict__ bias,
    float* __restrict__ out)
{
    __shared__ __align__(16) _Float16 y_sh[64 * CCH];   // 48 KB

    const int tid  = threadIdx.x;
    const int lane = tid & 63;
    const int g    = __builtin_amdgcn_readfirstlane(tid >> 6);  // wave 0..3
    const int cb   = g * 96;

    const int n  = blockIdx.z;
    const int h0 = blockIdx.y * 8;
    const int w0 = blockIdx.x * 8;
    const int hh = lane >> 3, ww = lane & 7;
    const int h = h0 + hh, w = w0 + ww;

    // ---- phase 1: depthwise 3x3, 8 channels per lane per chunk ----
    const float* xn = x + (size_t)n * CCH * HW2;
    for (int c8 = 0; c8 < 12; ++c8) {
        const int ci0 = cb + c8 * 8;
        const float* xc = xn + (size_t)ci0 * HW2;
        float a8[8] = {0.f, 0.f, 0.f, 0.f, 0.f, 0.f, 0.f, 0.f};
        #pragma unroll
        for (int r = 0; r < 3; ++r) {
            const int xh = h + r - 1;
            const bool okh = ((unsigned)xh < (unsigned)HH);
            #pragma unroll
            for (int s = 0; s < 3; ++s) {
                const int xw = w + s - 1;
                const bool ok = okh && ((unsigned)xw < (unsigned)WW);
                const float* xp = xc + xh * WW + xw;
                #pragma unroll
                for (int j = 0; j < 8; ++j) {
                    const float xv = ok ? xp[(size_t)j * HW2] : 0.f;
                    a8[j] = fmaf(xv, dwq[(ci0 + j) * 9 + r * 3 + s], a8[j]);
                }
            }
        }
        half8 hv;
        #pragma unroll
        for (int j = 0; j < 8; ++j) hv[j] = (_Float16)a8[j];
        const int off = (lane * 768 + ci0 * 2) ^ ((lane & 7) << 4);
        *(half8*)((char*)y_sh + off) = hv;
    }
    __syncthreads();

    // ---- phase 2: pointwise GEMM via MFMA ----
    const int lco = lane & 15;   // co-sub (A) / pos-sub (B) / D col
    const int lkg = lane >> 4;   // k-group

    f32x4 acc[6][4];
    #pragma unroll
    for (int mc = 0; mc < 6; ++mc)
        #pragma unroll
        for (int np = 0; np < 4; ++np)
            acc[mc][np] = (f32x4){0.f, 0.f, 0.f, 0.f};

    const int cbf = cb >> 4;     // wave's co-frag base (0,6,12,18)
    for (int kk = 0; kk < 12; ++kk) {
        half8 wf[6];
        #pragma unroll
        for (int mc = 0; mc < 6; ++mc)
            wf[mc] = *(const half8*)(wpk + (size_t)(kk * 24 + cbf + mc) * 512 + lane * 8);
        half8 yf[4];
        #pragma unroll
        for (int np = 0; np < 4; ++np) {
            const int pos = np * 16 + lco;
            int off = pos * 768 + (kk * 32 + lkg * 8) * 2;
            off ^= (pos & 7) << 4;
            yf[np] = *(const half8*)((const char*)y_sh + off);
        }
        #pragma unroll
        for (int mc = 0; mc < 6; ++mc)
            #pragma unroll
            for (int np = 0; np < 4; ++np)
                acc[mc][np] = __builtin_amdgcn_mfma_f32_16x16x32_f16(
                    wf[mc], yf[np], acc[mc][np], 0, 0, 0);
    }

    // ---- epilogue: bias + store ----
    float* ob = out + (size_t)n * CCH * HW2;
    #pragma unroll
    for (int mc = 0; mc < 6; ++mc) {
        #pragma unroll
        for (int r = 0; r < 4; ++r) {
            const int co = cb + mc * 16 + lkg * 4 + r;
            const float bv = bias[co];
            #pragma unroll
            for (int np = 0; np < 4; ++np) {
                const int pos = np * 16 + lco;
                const int oh = h0 + (pos >> 3), ow = w0 + (pos & 7);
                ob[(size_t)co * HW2 + oh * WW + ow] = acc[mc][np][r] + bv;
            }
        }
    }
}

// ---------------------------------------------------------------------------

extern "C" void kernel_launch(void* const* d_in, const int* in_sizes, int n_in,
                              void* d_out, int out_size, void* d_ws, size_t ws_size,
                              hipStream_t stream) {
    const float* x  = (const float*)d_in[0];
    const float* dw = (const float*)d_in[1];
    const float* pw = (const float*)d_in[2];
    const float* pb = (const float*)d_in[3];
    float* out = (float*)d_out;

    float*    dwq = (float*)d_ws;                 // 3456 f32
    _Float16* wpk = (_Float16*)(dwq + CCH * 9);   // 147456 fp16, MFMA-packed

    quant_dw<<<2, 256, 0, stream>>>(dw, dwq);
    quant_pw<<<CCH, 64, 0, stream>>>(pw, wpk);

    dim3 grid(WW / 8, HH / 8, 32);                // 7 x 7 x 32
    fused_conv<<<grid, 256, 0, stream>>>(x, dwq, wpk, pb, out);
}

// Round 3
// 197.018 us; speedup vs baseline: 4.2080x; 1.8113x over previous
//
#include <hip/hip_runtime.h>
#include <hip/hip_bf16.h>

#define CCH 384
#define HW2 3136
#define HH 56
#define WW 56
#define QMAX 7.0f
#define SCALE_MIN 2e-16f
#define NB 32
#define PB 49            // 64-pos blocks per image
#define YSLAB 512        // elems per (pb,c8) slab: 64 pos * 8 ci
#define YPB 24576        // 48 * 512 elems per pos-block

typedef _Float16 half8 __attribute__((ext_vector_type(8)));
typedef float f32x4 __attribute__((ext_vector_type(4)));

#define GLOAD_LDS16(g, l) __builtin_amdgcn_global_load_lds( \
    (const __attribute__((address_space(1))) void*)(g), \
    (__attribute__((address_space(3))) void*)(l), 16, 0, 0)

// ---------------- quant kernels (Brevitas per-channel symmetric int4) -------

__global__ void quant_dw(const float* __restrict__ dw, float* __restrict__ dwq) {
    int c = blockIdx.x * blockDim.x + threadIdx.x;
    if (c >= CCH) return;
    float w[9];
    float amax = 0.f;
    #pragma unroll
    for (int j = 0; j < 9; ++j) {
        w[j] = dw[c * 9 + j];
        amax = fmaxf(amax, fabsf(w[j]));
    }
    float scale = fmaxf(amax / QMAX, SCALE_MIN);
    #pragma unroll
    for (int j = 0; j < 9; ++j) {
        float q = rintf(w[j] / scale);          // round half-even = jnp.round
        q = fminf(fmaxf(q, -QMAX), QMAX);
        dwq[c * 9 + j] = q * scale;
    }
}

// one block (64 threads) per output channel; fake-quant then pack fp16 into
// MFMA A-fragment layout: wpk[(ci/32)*24 + co/16][lane][8]
__global__ void quant_pw(const float* __restrict__ pw, _Float16* __restrict__ wpk) {
    int co = blockIdx.x;
    int lane = threadIdx.x;
    float w[6];
    float amax = 0.f;
    #pragma unroll
    for (int j = 0; j < 6; ++j) {
        w[j] = pw[co * CCH + lane + j * 64];
        amax = fmaxf(amax, fabsf(w[j]));
    }
    #pragma unroll
    for (int off = 32; off >= 1; off >>= 1)
        amax = fmaxf(amax, __shfl_xor(amax, off));
    float scale = fmaxf(amax / QMAX, SCALE_MIN);
    #pragma unroll
    for (int j = 0; j < 6; ++j) {
        int ci = lane + j * 64;
        float q = rintf(w[j] / scale);
        q = fminf(fmaxf(q, -QMAX), QMAX);
        float v = q * scale;
        int kk  = ci >> 5;
        int cis = ci & 31;
        int l   = (co & 15) | ((cis >> 3) << 4);
        int idx = (kk * 24 + (co >> 4)) * 512 + l * 8 + (cis & 7);
        wpk[idx] = (_Float16)v;
    }
}

// ---------------- kernel A: depthwise 3x3 -> packed fp16 y ------------------
// thread = one flat position; all tap loads wave-contiguous (256B).
// Writes ypk[n][pb64][c8][pos&63][8ci] : per-lane 16B, per-wave 1KB contig.

__global__ __launch_bounds__(256) void dw_kernel(
    const float* __restrict__ x, const float* __restrict__ dwq,
    _Float16* __restrict__ ypk)
{
    // 416 blocks = 8 XCDs * 52 : chunked swizzle, consecutive tiles same XCD
    int bid = blockIdx.x;
    int wg = (bid & 7) * 52 + (bid >> 3);
    int n = wg / 13, pbB = wg % 13;
    int p = pbB * 256 + threadIdx.x;
    if (p >= HW2) return;
    int h = p / WW, w = p - h * WW;

    const float* xn = x + (size_t)n * CCH * HW2 + p;
    _Float16* yb = ypk + (size_t)(n * PB + (p >> 6)) * YPB + (p & 63) * 8;

    bool okh[3], okw[3];
    okh[0] = (h >= 1); okh[1] = true; okh[2] = (h <= HH - 2);
    okw[0] = (w >= 1); okw[1] = true; okw[2] = (w <= WW - 2);

    for (int c8 = 0; c8 < 48; ++c8) {
        const float* xp = xn + (size_t)c8 * 8 * HW2;
        const float* dk = dwq + c8 * 72;
        float a[8] = {0.f,0.f,0.f,0.f,0.f,0.f,0.f,0.f};
        #pragma unroll
        for (int r = 0; r < 3; ++r) {
            #pragma unroll
            for (int s = 0; s < 3; ++s) {
                const bool ok = okh[r] && okw[s];
                const int off = (r - 1) * WW + (s - 1);
                #pragma unroll
                for (int j = 0; j < 8; ++j) {
                    float xv = ok ? xp[(size_t)j * HW2 + off] : 0.f;
                    a[j] = fmaf(xv, dk[j * 9 + r * 3 + s], a[j]);
                }
            }
        }
        half8 hv;
        #pragma unroll
        for (int j = 0; j < 8; ++j) hv[j] = (_Float16)a[j];
        *(half8*)(yb + (size_t)c8 * YSLAB) = hv;
    }
}

// ---------------- kernel B: pointwise GEMM (384co x 384ci x 64pos/blk) ------
// Stage packed y tile (48KB) via global_load_lds, one barrier, then pure
// ds_read_b128 + MFMA. Weights stream from L2.

__global__ __launch_bounds__(256) void pw_kernel(
    const _Float16* __restrict__ ypk, const _Float16* __restrict__ wpk,
    const float* __restrict__ bias, float* __restrict__ out)
{
    __shared__ __align__(16) _Float16 ysh[YPB];   // 48 KB

    int bid = blockIdx.x;                 // 1568 = 8 * 196
    int wg = (bid & 7) * 196 + (bid >> 3);
    int n = wg / PB, pb = wg % PB;

    const int t = threadIdx.x;
    const int lane = t & 63;
    const int g = __builtin_amdgcn_readfirstlane(t >> 6);

    // ---- stage y tile: identity copy of the packed 48KB blob ----
    const _Float16* yg = ypk + (size_t)(n * PB + pb) * YPB;
    #pragma unroll
    for (int j = 0; j < 12; ++j) {
        GLOAD_LDS16(yg + (j * 256 + t) * 8,
                    ysh + (size_t)(j * 256 + (t & 192)) * 8);
    }
    __syncthreads();

    // ---- K-loop ----
    const int lco = lane & 15;
    const int lkg = lane >> 4;
    const int cbf = g * 6;

    f32x4 acc[6][4];
    #pragma unroll
    for (int mc = 0; mc < 6; ++mc)
        #pragma unroll
        for (int np = 0; np < 4; ++np)
            acc[mc][np] = (f32x4){0.f, 0.f, 0.f, 0.f};

    for (int kk = 0; kk < 12; ++kk) {
        half8 wf[6];
        #pragma unroll
        for (int mc = 0; mc < 6; ++mc)
            wf[mc] = *(const half8*)(wpk + (size_t)(kk * 24 + cbf + mc) * 512 + lane * 8);
        half8 yf[4];
        #pragma unroll
        for (int np = 0; np < 4; ++np)
            yf[np] = *(const half8*)(ysh + kk * 2048 + lkg * 512 + (np * 16 + lco) * 8);
        #pragma unroll
        for (int mc = 0; mc < 6; ++mc)
            #pragma unroll
            for (int np = 0; np < 4; ++np)
                acc[mc][np] = __builtin_amdgcn_mfma_f32_16x16x32_f16(
                    wf[mc], yf[np], acc[mc][np], 0, 0, 0);
    }

    // ---- epilogue: bias + store ----
    float* ob = out + (size_t)n * CCH * HW2 + (size_t)pb * 64;
    #pragma unroll
    for (int mc = 0; mc < 6; ++mc) {
        #pragma unroll
        for (int r = 0; r < 4; ++r) {
            const int co = g * 96 + mc * 16 + lkg * 4 + r;
            const float bv = bias[co];
            #pragma unroll
            for (int np = 0; np < 4; ++np)
                ob[(size_t)co * HW2 + np * 16 + lco] = acc[mc][np][r] + bv;
        }
    }
}

// ---------------------------------------------------------------------------

extern "C" void kernel_launch(void* const* d_in, const int* in_sizes, int n_in,
                              void* d_out, int out_size, void* d_ws, size_t ws_size,
                              hipStream_t stream) {
    const float* x  = (const float*)d_in[0];
    const float* dw = (const float*)d_in[1];
    const float* pw = (const float*)d_in[2];
    const float* pb = (const float*)d_in[3];
    float* out = (float*)d_out;

    float*    dwq = (float*)d_ws;                         // 3456 f32
    _Float16* wpk = (_Float16*)(dwq + CCH * 9);           // 147456 fp16
    _Float16* ypk = wpk + (size_t)CCH * CCH;              // 38.5M fp16 (77 MB)

    quant_dw<<<2, 256, 0, stream>>>(dw, dwq);
    quant_pw<<<CCH, 64, 0, stream>>>(pw, wpk);

    dw_kernel<<<416, 256, 0, stream>>>(x, dwq, ypk);
    pw_kernel<<<1568, 256, 0, stream>>>(ypk, wpk, pb, out);
}

// Round 4
// 191.874 us; speedup vs baseline: 4.3208x; 1.0268x over previous
//
#include <hip/hip_runtime.h>
#include <hip/hip_bf16.h>

#define CCH 384
#define HW2 3136
#define HH 56
#define WW 56
#define QMAX 7.0f
#define SCALE_MIN 2e-16f
#define PB 49            // 64-pos blocks per image
#define YSLAB 512        // elems per (pb,c8) slab: 64 pos * 8 ci
#define YPB 24576        // 48 * 512 elems per pos-block

typedef _Float16 half8 __attribute__((ext_vector_type(8)));
typedef float f32x4 __attribute__((ext_vector_type(4)));

#define GLOAD_LDS16(g, l) __builtin_amdgcn_global_load_lds( \
    (const __attribute__((address_space(1))) void*)(g), \
    (__attribute__((address_space(3))) void*)(l), 16, 0, 0)

// ---------------- quant kernels (Brevitas per-channel symmetric int4) -------

__global__ void quant_dw(const float* __restrict__ dw, float* __restrict__ dwq) {
    int c = blockIdx.x * blockDim.x + threadIdx.x;
    if (c >= CCH) return;
    float w[9];
    float amax = 0.f;
    #pragma unroll
    for (int j = 0; j < 9; ++j) {
        w[j] = dw[c * 9 + j];
        amax = fmaxf(amax, fabsf(w[j]));
    }
    float scale = fmaxf(amax / QMAX, SCALE_MIN);
    #pragma unroll
    for (int j = 0; j < 9; ++j) {
        float q = rintf(w[j] / scale);          // round half-even = jnp.round
        q = fminf(fmaxf(q, -QMAX), QMAX);
        dwq[c * 9 + j] = q * scale;
    }
}

// one block (64 threads) per output channel; fake-quant then pack fp16 into
// MFMA A-fragment layout: wpk[(ci/32)*24 + co/16][lane][8]
__global__ void quant_pw(const float* __restrict__ pw, _Float16* __restrict__ wpk) {
    int co = blockIdx.x;
    int lane = threadIdx.x;
    float w[6];
    float amax = 0.f;
    #pragma unroll
    for (int j = 0; j < 6; ++j) {
        w[j] = pw[co * CCH + lane + j * 64];
        amax = fmaxf(amax, fabsf(w[j]));
    }
    #pragma unroll
    for (int off = 32; off >= 1; off >>= 1)
        amax = fmaxf(amax, __shfl_xor(amax, off));
    float scale = fmaxf(amax / QMAX, SCALE_MIN);
    #pragma unroll
    for (int j = 0; j < 6; ++j) {
        int ci = lane + j * 64;
        float q = rintf(w[j] / scale);
        q = fminf(fmaxf(q, -QMAX), QMAX);
        float v = q * scale;
        int kk  = ci >> 5;
        int cis = ci & 31;
        int l   = (co & 15) | ((cis >> 3) << 4);
        int idx = (kk * 24 + (co >> 4)) * 512 + l * 8 + (cis & 7);
        wpk[idx] = (_Float16)v;
    }
}

// ---------------- kernel A: depthwise 3x3 -> packed fp16 y ------------------
// thread = one flat position; block = 256 positions x 64 channels (8 c8).
// All tap loads wave-contiguous (256B). Writes ypk[n][pb][c8][pos&63][8ci].

__global__ __launch_bounds__(256) void dw_kernel(
    const float* __restrict__ x, const float* __restrict__ dwq,
    _Float16* __restrict__ ypk)
{
    // 2496 blocks = 8 XCDs * 312 : chunked swizzle
    int bid = blockIdx.x;
    int wg = (bid & 7) * 312 + (bid >> 3);
    int n = wg / 78;
    int rem = wg % 78;
    int pbB = rem / 6;            // 0..12  (256-position chunk)
    int cgr = rem % 6;            // 0..5   (64-channel group)

    int p = pbB * 256 + threadIdx.x;
    if (p >= HW2) return;
    int h = p / WW, w = p - h * WW;

    const int c8base = cgr * 8;
    const float* xn = x + (size_t)n * CCH * HW2 + (size_t)c8base * 8 * HW2 + p;
    _Float16* yb = ypk + (size_t)(n * PB + (p >> 6)) * YPB
                       + (size_t)c8base * YSLAB + (p & 63) * 8;

    bool okh[3], okw[3];
    okh[0] = (h >= 1); okh[1] = true; okh[2] = (h <= HH - 2);
    okw[0] = (w >= 1); okw[1] = true; okw[2] = (w <= WW - 2);

    #pragma unroll
    for (int c8 = 0; c8 < 8; ++c8) {
        const float* xp = xn + (size_t)c8 * 8 * HW2;
        const float* dk = dwq + (c8base + c8) * 72;
        float a[8] = {0.f,0.f,0.f,0.f,0.f,0.f,0.f,0.f};
        #pragma unroll
        for (int r = 0; r < 3; ++r) {
            #pragma unroll
            for (int s = 0; s < 3; ++s) {
                const bool ok = okh[r] && okw[s];
                const int off = (r - 1) * WW + (s - 1);
                #pragma unroll
                for (int j = 0; j < 8; ++j) {
                    float xv = ok ? xp[(size_t)j * HW2 + off] : 0.f;
                    a[j] = fmaf(xv, dk[j * 9 + r * 3 + s], a[j]);
                }
            }
        }
        half8 hv;
        #pragma unroll
        for (int j = 0; j < 8; ++j) hv[j] = (_Float16)a[j];
        *(half8*)(yb + (size_t)c8 * YSLAB) = hv;
    }
}

// ---------------- kernel B: pointwise GEMM (384co x 384ci x 64pos/blk) ------

__global__ __launch_bounds__(256) void pw_kernel(
    const _Float16* __restrict__ ypk, const _Float16* __restrict__ wpk,
    const float* __restrict__ bias, float* __restrict__ out)
{
    __shared__ __align__(16) _Float16 ysh[YPB];   // 48 KB

    int bid = blockIdx.x;                 // 1568 = 8 * 196
    int wg = (bid & 7) * 196 + (bid >> 3);
    int n = wg / PB, pb = wg % PB;

    const int t = threadIdx.x;
    const int lane = t & 63;
    const int g = __builtin_amdgcn_readfirstlane(t >> 6);

    // ---- stage y tile: identity copy of the packed 48KB blob ----
    const _Float16* yg = ypk + (size_t)(n * PB + pb) * YPB;
    #pragma unroll
    for (int j = 0; j < 12; ++j) {
        GLOAD_LDS16(yg + (j * 256 + t) * 8,
                    ysh + (size_t)(j * 256 + (t & 192)) * 8);
    }
    __syncthreads();

    // ---- K-loop ----
    const int lco = lane & 15;
    const int lkg = lane >> 4;
    const int cbf = g * 6;

    f32x4 acc[6][4];
    #pragma unroll
    for (int mc = 0; mc < 6; ++mc)
        #pragma unroll
        for (int np = 0; np < 4; ++np)
            acc[mc][np] = (f32x4){0.f, 0.f, 0.f, 0.f};

    for (int kk = 0; kk < 12; ++kk) {
        half8 wf[6];
        #pragma unroll
        for (int mc = 0; mc < 6; ++mc)
            wf[mc] = *(const half8*)(wpk + (size_t)(kk * 24 + cbf + mc) * 512 + lane * 8);
        half8 yf[4];
        #pragma unroll
        for (int np = 0; np < 4; ++np)
            yf[np] = *(const half8*)(ysh + kk * 2048 + lkg * 512 + (np * 16 + lco) * 8);
        #pragma unroll
        for (int mc = 0; mc < 6; ++mc)
            #pragma unroll
            for (int np = 0; np < 4; ++np)
                acc[mc][np] = __builtin_amdgcn_mfma_f32_16x16x32_f16(
                    wf[mc], yf[np], acc[mc][np], 0, 0, 0);
    }

    // ---- epilogue: bias + store ----
    float* ob = out + (size_t)n * CCH * HW2 + (size_t)pb * 64;
    #pragma unroll
    for (int mc = 0; mc < 6; ++mc) {
        #pragma unroll
        for (int r = 0; r < 4; ++r) {
            const int co = g * 96 + mc * 16 + lkg * 4 + r;
            const float bv = bias[co];
            #pragma unroll
            for (int np = 0; np < 4; ++np)
                ob[(size_t)co * HW2 + np * 16 + lco] = acc[mc][np][r] + bv;
        }
    }
}

// ---------------------------------------------------------------------------

extern "C" void kernel_launch(void* const* d_in, const int* in_sizes, int n_in,
                              void* d_out, int out_size, void* d_ws, size_t ws_size,
                              hipStream_t stream) {
    const float* x  = (const float*)d_in[0];
    const float* dw = (const float*)d_in[1];
    const float* pw = (const float*)d_in[2];
    const float* pb = (const float*)d_in[3];
    float* out = (float*)d_out;

    float*    dwq = (float*)d_ws;                         // 3456 f32
    _Float16* wpk = (_Float16*)(dwq + CCH * 9);           // 147456 fp16
    _Float16* ypk = wpk + (size_t)CCH * CCH;              // 38.5M fp16 (77 MB)

    quant_dw<<<2, 256, 0, stream>>>(dw, dwq);
    quant_pw<<<CCH, 64, 0, stream>>>(pw, wpk);

    dw_kernel<<<2496, 256, 0, stream>>>(x, dwq, ypk);
    pw_kernel<<<1568, 256, 0, stream>>>(ypk, wpk, pb, out);
}